// Round 5
// baseline (225.088 us; speedup 1.0000x reference)
//
#include <hip/hip_runtime.h>

#define FDIM 512
#define CDIM 64
#define NLEAF 1024
#define MAT (FDIM * CDIM)            /* 32768 floats per node */
#define OUT_LOGITS (NLEAF * CDIM)    /* 65536 */
#define WS_REG (1024 * 256)          /* offset of reg partials in ws (floats) */

__device__ __forceinline__ float abs4(const float4 v) {
    return fabsf(v.x) + fabsf(v.y) + fabsf(v.z) + fabsf(v.w);
}
__device__ __forceinline__ float sq4(const float4 v) {
    return v.x * v.x + v.y * v.y + v.z * v.z + v.w * v.w;
}

// Stream 4 rows (f..f+3) x this thread's c-quad of one node; FMA into acc[R0..R1).
// H selects which half of the 8-f window the x fragment covers.
// MODE: 1 = L1*scale, 2 = squared (root)
template<int R0, int R1, int H, int MODE>
__device__ __forceinline__ void seg4(const float* __restrict__ p,
                                     const float4 xr[4][2],
                                     float4* __restrict__ acc,
                                     float& rl1, float& rsq, float scale)
{
    const float4 d0 = *(const float4*)(p);
    const float4 d1 = *(const float4*)(p + CDIM);
    const float4 d2 = *(const float4*)(p + 2 * CDIM);
    const float4 d3 = *(const float4*)(p + 3 * CDIM);
    if (MODE == 1) rl1 = fmaf(abs4(d0) + abs4(d1) + abs4(d2) + abs4(d3), scale, rl1);
    if (MODE == 2) rsq += sq4(d0) + sq4(d1) + sq4(d2) + sq4(d3);
#pragma unroll
    for (int r = R0; r < R1; ++r) {
        const float4 xv = xr[r][H];
        acc[r].x += xv.x * d0.x + xv.y * d1.x + xv.z * d2.x + xv.w * d3.x;
        acc[r].y += xv.x * d0.y + xv.y * d1.y + xv.z * d2.y + xv.w * d3.y;
        acc[r].z += xv.x * d0.z + xv.y * d1.z + xv.z * d2.z + xv.w * d3.z;
        acc[r].w += xv.x * d0.w + xv.y * d1.w + xv.z * d2.w + xv.w * d3.w;
    }
}

// Stream this thread's full 8-f x 4-c tile of one node (8 float4 loads).
template<int R0, int R1, int MODE>
__device__ __forceinline__ void node8(const float* __restrict__ p,
                                      const float4 xr[4][2],
                                      float4* __restrict__ acc,
                                      float& rl1, float& rsq, float scale)
{
    seg4<R0, R1, 0, MODE>(p,            xr, acc, rl1, rsq, scale);
    seg4<R0, R1, 1, MODE>(p + 4 * CDIM, xr, acc, rl1, rsq, scale);
}

// ---------------------------------------------------------------------------
// One block = (group of 4 sibling leaves) x (128-wide f-slice). 1024 blocks.
// Branchless stream of the 9 path nodes (root,d1..d4,4 leaves), 72 float4
// loads per thread, root->leaf order so co-resident blocks share ancestor
// reads via L2. Reg terms folded in with precomputed scales (0 = non-owner).
// Partial logits -> ws (no atomics); reg partial -> ws[WS_REG + ...].
// ---------------------------------------------------------------------------
__global__ __launch_bounds__(256, 4) void k_stream(const float* __restrict__ x,
                                                   const float* __restrict__ deltas,
                                                   const float* __restrict__ heights,
                                                   float* __restrict__ ws)
{
    __shared__ float red[4 * 16 * 20];   // [wave][cq][16], stride 20 pad
    __shared__ float rr[4];

    const int tid = threadIdx.x;
    const int bid = blockIdx.x;
    // XCD-aware mapping: XCD k = bid&7 owns groups [32k, 32k+32) for all 4 fs
    const int k  = bid & 7;
    const int t  = bid >> 3;
    const int fs = t >> 5;                 // f-slice 0..3
    const int g  = (k << 5) | (t & 31);    // leaf group 0..255 (leaves 4g..4g+3)
    const int fg = tid >> 4;               // 0..15
    const int cq = tid & 15;               // c-quad
    const int f0 = fs * 128 + fg * 8;      // this thread's 8-f window
    const int l0 = g * 4;

    // x fragments: 4 leaves x 8 f = 8 float4 (32 VGPR)
    float4 xr[4][2];
#pragma unroll
    for (int r = 0; r < 4; ++r)
#pragma unroll
        for (int h = 0; h < 2; ++h)
            xr[r][h] = *(const float4*)(x + (size_t)(l0 + r) * FDIM + f0 + 4 * h);

    // path node ids
    const int n1 = 1 + (g >> 6), n2 = 5 + (g >> 4), n3 = 21 + (g >> 2);
    const int n4 = 85 + g, nl = 341 + 4 * g;

    // reg scales (0 when this group doesn't own the node)
    const float h0 = heights[0], h1 = heights[n1], h2 = heights[n2];
    const float h3 = heights[n3], h4 = heights[n4];
    const float s1 = ((g & 63) == 0) ? 1.f / fmaxf(fabsf(h1 - h0), 1e-7f) : 0.f;
    const float s2 = ((g & 15) == 0) ? 1.f / fmaxf(fabsf(h2 - h1), 1e-7f) : 0.f;
    const float s3 = ((g & 3)  == 0) ? 1.f / fmaxf(fabsf(h3 - h2), 1e-7f) : 0.f;
    const float s4 = 1.f / fmaxf(fabsf(h4 - h3), 1e-7f);
    float sl[4];
#pragma unroll
    for (int j = 0; j < 4; ++j)
        sl[j] = 1.f / fmaxf(fabsf(heights[nl + j] - h4), 1e-7f);

    const size_t toff = (size_t)f0 * CDIM + (size_t)cq * 4;
    float4 acc[4];
#pragma unroll
    for (int r = 0; r < 4; ++r) acc[r] = make_float4(0.f, 0.f, 0.f, 0.f);
    float rl1 = 0.f, rsq = 0.f;

    // ---- branchless root->leaf stream (72 independent float4 loads)
    node8<0, 4, 2>(deltas + toff,                           xr, acc, rl1, rsq, 0.f);
    node8<0, 4, 1>(deltas + (size_t)n1 * MAT + toff,        xr, acc, rl1, rsq, s1);
    node8<0, 4, 1>(deltas + (size_t)n2 * MAT + toff,        xr, acc, rl1, rsq, s2);
    node8<0, 4, 1>(deltas + (size_t)n3 * MAT + toff,        xr, acc, rl1, rsq, s3);
    node8<0, 4, 1>(deltas + (size_t)n4 * MAT + toff,        xr, acc, rl1, rsq, s4);
    node8<0, 1, 1>(deltas + (size_t)(nl + 0) * MAT + toff,  xr, acc, rl1, rsq, sl[0]);
    node8<1, 2, 1>(deltas + (size_t)(nl + 1) * MAT + toff,  xr, acc, rl1, rsq, sl[1]);
    node8<2, 3, 1>(deltas + (size_t)(nl + 2) * MAT + toff,  xr, acc, rl1, rsq, sl[2]);
    node8<3, 4, 1>(deltas + (size_t)(nl + 3) * MAT + toff,  xr, acc, rl1, rsq, sl[3]);

    // ---- reduce over the 4 fg values inside each wave (lane bits 4,5)
#pragma unroll
    for (int r = 0; r < 4; ++r) {
        acc[r].x += __shfl_xor(acc[r].x, 16, 64);  acc[r].x += __shfl_xor(acc[r].x, 32, 64);
        acc[r].y += __shfl_xor(acc[r].y, 16, 64);  acc[r].y += __shfl_xor(acc[r].y, 32, 64);
        acc[r].z += __shfl_xor(acc[r].z, 16, 64);  acc[r].z += __shfl_xor(acc[r].z, 32, 64);
        acc[r].w += __shfl_xor(acc[r].w, 16, 64);  acc[r].w += __shfl_xor(acc[r].w, 32, 64);
    }

    const int w = tid >> 6, lane = tid & 63;
    if (lane < 16) {
#pragma unroll
        for (int r = 0; r < 4; ++r)
            *(float4*)(red + (w * 16 + cq) * 20 + r * 4) = acc[r];
    }

    // ---- reg partial: wave butterfly -> LDS
    float r2 = rl1 + ((g == 0) ? rsq : 0.f);
#pragma unroll
    for (int off = 1; off < 64; off <<= 1) r2 += __shfl_xor(r2, off, 64);
    if (lane == 0) rr[w] = r2;
    __syncthreads();

    // ---- write 256 partial logits (coalesced, no atomics)
    {
        const int r = tid >> 6, c = tid & 63;
        float v = 0.f;
#pragma unroll
        for (int w2 = 0; w2 < 4; ++w2)
            v += red[(w2 * 16 + (c >> 2)) * 20 + r * 4 + (c & 3)];
        ws[(size_t)(g * 4 + fs) * 256 + tid] = v;
    }
    if (tid == 0)
        ws[WS_REG + g * 4 + fs] = rr[0] + rr[1] + rr[2] + rr[3];
}

// ---------------------------------------------------------------------------
// Finish: sum the 4 f-slice partials per leaf, softmax, write out.
// One 64-lane wave per leaf row. 256 blocks x 256 threads.
// ---------------------------------------------------------------------------
__global__ __launch_bounds__(256) void k_finish(const float* __restrict__ ws,
                                                float* __restrict__ out)
{
    const int l = blockIdx.x * 4 + (threadIdx.x >> 6);
    const int c = threadIdx.x & 63;
    const int g = l >> 2, r = l & 3;
    float v = 0.f;
#pragma unroll
    for (int fs = 0; fs < 4; ++fs)
        v += ws[(size_t)(g * 4 + fs) * 256 + r * 64 + c];
    float m = v;
#pragma unroll
    for (int off = 32; off > 0; off >>= 1) m = fmaxf(m, __shfl_xor(m, off, 64));
    const float e = expf(v - m);
    float s = e;
#pragma unroll
    for (int off = 32; off > 0; off >>= 1) s += __shfl_xor(s, off, 64);
    out[(size_t)l * CDIM + c] = e / s;
}

// ---------------------------------------------------------------------------
// Sum the 1024 reg partials -> out[OUT_LOGITS]
// ---------------------------------------------------------------------------
__global__ __launch_bounds__(256) void k_regsum(const float* __restrict__ ws,
                                                float* __restrict__ out)
{
    __shared__ float r[4];
    const int tid = threadIdx.x;
    const float* p = ws + WS_REG;
    float v = p[tid] + p[256 + tid] + p[512 + tid] + p[768 + tid];
#pragma unroll
    for (int off = 1; off < 64; off <<= 1) v += __shfl_xor(v, off, 64);
    if ((tid & 63) == 0) r[tid >> 6] = v;
    __syncthreads();
    if (tid == 0) out[OUT_LOGITS] = r[0] + r[1] + r[2] + r[3];
}

extern "C" void kernel_launch(void* const* d_in, const int* in_sizes, int n_in,
                              void* d_out, int out_size, void* d_ws, size_t ws_size,
                              hipStream_t stream)
{
    const float* x       = (const float*)d_in[0];
    const float* deltas  = (const float*)d_in[1];
    const float* heights = (const float*)d_in[2];
    float* out = (float*)d_out;
    float* ws  = (float*)d_ws;

    k_stream<<<1024, 256, 0, stream>>>(x, deltas, heights, ws);
    k_finish<<<256, 256, 0, stream>>>(ws, out);
    k_regsum<<<1, 256, 0, stream>>>(ws, out);
}